// Round 1
// 104.949 us; speedup vs baseline: 1.1074x; 1.1074x over previous
//
#include <hip/hip_runtime.h>
#include <hip/hip_bf16.h>

// Problem constants
#define B_      4
#define C_IN    64
#define H_      64
#define W_      64
#define OUT_CH  128
#define HP_     66          // padded height (halo = features(0))
#define CF      576         // K per tap: 9 features * 64 channels, cf = j*64 + c
#define WP_BYTES  (9 * OUT_CH * CF * 2)          // 1,327,104
#define F_BYTES   (B_ * HP_ * HP_ * CF * 2)      // 20,072,448
#define P_OFFSET  (WP_BYTES + F_BYTES)           // 21,399,552 (16B aligned)
// partials: 4 K-groups x (4 b x 128 o x 4096 pix) fp16 = 16,777,216 B

typedef __bf16 bf16x8 __attribute__((ext_vector_type(8)));
typedef float  f32x4  __attribute__((ext_vector_type(4)));
typedef _Float16 half8 __attribute__((ext_vector_type(8)));

// silu + cubic B-spline bases (Cox-de Boor), identical semantics to passing rounds.
__device__ __forceinline__ void compute_features(float x, float f[9]) {
    f[0] = x / (1.0f + __expf(-x));
    float g[12];
#pragma unroll
    for (int i = 0; i < 12; ++i) g[i] = (float)(i - 3) * 0.4f - 1.0f;
    float bb[11];
#pragma unroll
    for (int i = 0; i < 11; ++i) bb[i] = (x >= g[i] && x < g[i + 1]) ? 1.0f : 0.0f;
#pragma unroll
    for (int i = 0; i < 10; ++i)
        bb[i] = (x - g[i]) * (1.0f / (g[i + 1] - g[i])) * bb[i]
              + (g[i + 2] - x) * (1.0f / (g[i + 2] - g[i + 1])) * bb[i + 1];
#pragma unroll
    for (int i = 0; i < 9; ++i)
        bb[i] = (x - g[i]) * (1.0f / (g[i + 2] - g[i])) * bb[i]
              + (g[i + 3] - x) * (1.0f / (g[i + 3] - g[i + 1])) * bb[i + 1];
#pragma unroll
    for (int i = 0; i < 8; ++i)
        bb[i] = (x - g[i]) * (1.0f / (g[i + 3] - g[i])) * bb[i]
              + (g[i + 4] - x) * (1.0f / (g[i + 4] - g[i + 1])) * bb[i + 1];
#pragma unroll
    for (int i = 0; i < 8; ++i) f[1 + i] = bb[i];
}

// Kernel 1 (merged): blocks 0..527  = features (one half-row each, 2x the old grid),
//                    blocks 528..3119 = weight pack (identical math to v2 pack).
// Merging removes one launch and lets the trivial pack blocks backfill CUs while
// the expf-heavy feat blocks run; the half-row split doubles waves/SIMD for feat.
__global__ __launch_bounds__(256) void prep_kernel(
        const float* __restrict__ x, __hip_bfloat16* __restrict__ F,
        const float* __restrict__ bw, const float* __restrict__ sw,
        const float* __restrict__ sc, __hip_bfloat16* __restrict__ Wp) {
    __shared__ float xs[64][33];
    int blk = blockIdx.x;
    int tid = threadIdx.x;

    if (blk >= 528) {                                   // ---- pack part ----
        int idx = (blk - 528) * 256 + tid;              // 0 .. 663551
        if (idx < 589824) {                             // spline: idx = o*4608 + d*8 + j
            int o = idx / 4608;
            int r = idx - o * 4608;
            int d = r >> 3;
            int j = r & 7;
            int tap = d % 9;
            int c   = d / 9;
            float v = sw[idx] * sc[o * 576 + d];
            Wp[(tap * OUT_CH + o) * CF + (j + 1) * 64 + c] = __float2bfloat16(v);
        } else {                                        // base: k = o*576 + d
            int k = idx - 589824;
            int o = k / 576;
            int d = k - o * 576;
            int tap = d % 9;
            int c   = d / 9;
            Wp[(tap * OUT_CH + o) * CF + c] = __float2bfloat16(bw[k]);
        }
        return;
    }

    // ---- feat part: one (b, hp, half-row) per block ----
    int half = blk & 1;                 // 0: w in [0,32)  1: w in [32,64)
    int bh   = blk >> 1;
    int b  = bh / HP_;
    int hp = bh % HP_;
    int h  = hp - 1;

    float f0[9];
    compute_features(0.0f, f0);

    bool interior_row = (h >= 0) && (h < H_);
    if (interior_row) {
        int wl = tid & 31;
        int c8 = tid >> 5;              // 0..7
#pragma unroll
        for (int i = 0; i < 8; ++i) {
            int c = c8 * 8 + i;
            xs[c][wl] = x[((b * C_IN + c) * H_ + h) * W_ + half * 32 + wl];
        }
    }
    __syncthreads();

    int c  = tid & 63;
    int wg = tid >> 6;                  // 0..3
    __hip_bfloat16* Frow = F + (size_t)((b * HP_ + hp) * HP_) * CF;

    if (!interior_row) {                // hp = 0 or 65: constant features over wp range
        for (int wp = half * 33 + wg; wp < half * 33 + 33; wp += 4) {
            __hip_bfloat16* dst = Frow + (size_t)wp * CF + c;
#pragma unroll
            for (int j = 0; j < 9; ++j) dst[j * 64] = __float2bfloat16(f0[j]);
        }
        return;
    }
    // wp halos
    if (half == 0 && wg == 0) {
        __hip_bfloat16* dst = Frow + c;                      // wp = 0
#pragma unroll
        for (int j = 0; j < 9; ++j) dst[j * 64] = __float2bfloat16(f0[j]);
    }
    if (half == 1 && wg == 3) {
        __hip_bfloat16* dst = Frow + (size_t)65 * CF + c;    // wp = 65
#pragma unroll
        for (int j = 0; j < 9; ++j) dst[j * 64] = __float2bfloat16(f0[j]);
    }
    // interior: 8 pixels/thread (was 16)
    for (int w2l = wg; w2l < 32; w2l += 4) {
        float xv = xs[c][w2l];          // bank (c + w2l) % 32 -> 2-way, free
        float f[9];
        compute_features(xv, f);
        int wp = half * 32 + w2l + 1;
        __hip_bfloat16* dst = Frow + (size_t)wp * CF + c;
#pragma unroll
        for (int j = 0; j < 9; ++j) dst[j * 64] = __float2bfloat16(f[j]);
    }
}

// Kernel 2: implicit-GEMM conv, 4-way K-split.
// v3: counted-vmcnt pipeline (T4). Depth-2 prologue (16 loads in flight / wave);
// per chunk: s_waitcnt vmcnt(8)+s_barrier (buf ready, next chunk still flying) ->
// hoist all 16 ds_read_b128 fragments -> lgkmcnt(0)+s_barrier (readers done) ->
// issue prefetch(ch+2) EARLY -> setprio(1) 32 MFMA setprio(0). vmcnt never drains
// to 0 in the main loop (only last iteration). Each wave issues exactly 8
// global_load_lds per chunk, so vmcnt(8) == "previous chunk landed".
__global__ __launch_bounds__(256, 2) void gemm_kernel(
        const __hip_bfloat16* __restrict__ Fb, const __hip_bfloat16* __restrict__ Wpb,
        _Float16* __restrict__ P) {
    __shared__ __align__(16) ushort As[2][8192];   // pixels:  [pix 0..127][cf 0..63] swizzled
    __shared__ __align__(16) ushort Bs[2][8192];   // weights: [o 0..127][cf 0..63] swizzled

    const ushort* F  = (const ushort*)Fb;
    const ushort* Wp = (const ushort*)Wpb;

    int tid  = threadIdx.x;
    int lane = tid & 63;
    int w    = tid >> 6;
    int l15  = lane & 15;
    int lq   = lane >> 4;
    int wm = w & 1;                  // out_ch half
    int wn = w >> 1;                 // pixel half
    int srow = lane >> 3;            // 0..7 staging sub-row
    int sl7  = lane & 7;
    int c8s  = sl7 ^ srow;           // staged c8 for this lane (swizzle-inverse)

    int blk = blockIdx.x;
    int g   = blk >> 7;              // K-group 0..3
    int t   = blk & 127;
    int b   = t >> 5;
    int ho0 = (t & 31) << 1;
    int c0 = (g == 0) ? 0 : (21 + 20 * (g - 1));   // {0,21,41,61}
    int c1 = c0 + ((g == 0) ? 21 : 20);            // 81 chunks total (tap*9 + kc)

    f32x4 acc[4][4];
#pragma unroll
    for (int i = 0; i < 4; ++i)
#pragma unroll
        for (int j = 0; j < 4; ++j) acc[i][j] = (f32x4){0.f, 0.f, 0.f, 0.f};

    auto prefetch = [&](int ch, int buf) {
        int tap = ch / 9;
        int kc  = ch - tap * 9;
        int kh  = tap / 3;
        int kw  = tap - kh * 3;
#pragma unroll
        for (int r = 0; r < 4; ++r) {
            int row = (r * 4 + w) * 8 + srow;       // 0..127 (pix or o)
            // A: features, tap-shifted pixel
            int hp = ho0 + (row >> 6) + kh;
            int wp = (row & 63) + kw;
            const ushort* srcA = F + (size_t)((b * HP_ + hp) * HP_ + wp) * CF
                                   + kc * 64 + c8s * 8;
            __builtin_amdgcn_global_load_lds(
                (const __attribute__((address_space(1))) unsigned int*)srcA,
                (__attribute__((address_space(3))) unsigned int*)&As[buf][(r * 4 + w) * 512],
                16, 0, 0);
            // B: weights
            const ushort* srcB = Wp + (size_t)(tap * OUT_CH + row) * CF
                                    + kc * 64 + c8s * 8;
            __builtin_amdgcn_global_load_lds(
                (const __attribute__((address_space(1))) unsigned int*)srcB,
                (__attribute__((address_space(3))) unsigned int*)&Bs[buf][(r * 4 + w) * 512],
                16, 0, 0);
        }
    };

    int buf = 0;
    prefetch(c0, 0);                 //  8 loads in flight
    prefetch(c0 + 1, 1);             // 16 in flight (c1-c0 >= 20 always)
    for (int ch = c0; ch < c1; ++ch) {
        // buf's 8 loads are the oldest outstanding; keep next chunk's 8 flying.
        if (ch + 1 < c1) asm volatile("s_waitcnt vmcnt(8)\n\ts_barrier" ::: "memory");
        else             asm volatile("s_waitcnt vmcnt(0)\n\ts_barrier" ::: "memory");

        // hoist all fragments for both K-halves into registers
        bf16x8 af[2][4], bq[2][4];
#pragma unroll
        for (int ks = 0; ks < 2; ++ks) {
#pragma unroll
            for (int mt = 0; mt < 4; ++mt) {
                int o  = wm * 64 + mt * 16 + l15;
                int sl = o * 8 + ((ks * 4 + lq) ^ (o & 7));
                af[ks][mt] = *(const bf16x8*)&Bs[buf][sl * 8];
            }
#pragma unroll
            for (int nt = 0; nt < 4; ++nt) {
                int p  = wn * 64 + nt * 16 + l15;
                int sl = p * 8 + ((ks * 4 + lq) ^ (p & 7));
                bq[ks][nt] = *(const bf16x8*)&As[buf][sl * 8];
            }
        }
        // my reads of buf complete -> safe for everyone to overwrite after barrier
        asm volatile("s_waitcnt lgkmcnt(0)\n\ts_barrier" ::: "memory");
        if (ch + 2 < c1) prefetch(ch + 2, buf);   // issue early: hides under MFMAs

        __builtin_amdgcn_s_setprio(1);
#pragma unroll
        for (int ks = 0; ks < 2; ++ks)
#pragma unroll
            for (int mt = 0; mt < 4; ++mt)
#pragma unroll
                for (int nt = 0; nt < 4; ++nt)
                    acc[mt][nt] = __builtin_amdgcn_mfma_f32_16x16x32_bf16(
                        af[ks][mt], bq[ks][nt], acc[mt][nt], 0, 0, 0);
        __builtin_amdgcn_s_setprio(0);
        buf ^= 1;
    }

    // epilogue: fp16 partials. P[((g*4+b)*128 + o)*4096 + ho0*64 + pix]
    _Float16* Pg = P + ((size_t)(g * 4 + b) * OUT_CH) * 4096 + ho0 * 64;
#pragma unroll
    for (int mt = 0; mt < 4; ++mt) {
        int o = wm * 64 + mt * 16 + lq * 4;
#pragma unroll
        for (int nt = 0; nt < 4; ++nt) {
            int pix = wn * 64 + nt * 16 + l15;
            _Float16* dst = Pg + (size_t)o * 4096 + pix;
#pragma unroll
            for (int r = 0; r < 4; ++r)
                dst[(size_t)r * 4096] = (_Float16)acc[mt][nt][r];
        }
    }
}

// Kernel 3: reduce 4 fp16 partials -> fp32 out. Fully coalesced half8/float4.
__global__ __launch_bounds__(256) void reduce_kernel(
        const half8* __restrict__ P, float4* __restrict__ out) {
    const int GS = 262144;                    // half8 per K-group (4*128*4096/8)
    int i = blockIdx.x * 256 + threadIdx.x;   // 0..262143
    half8 a = P[i], bb = P[GS + i], c = P[2 * GS + i], d = P[3 * GS + i];
    float4 o0, o1;
#pragma unroll
    for (int j = 0; j < 4; ++j)
        ((float*)&o0)[j] = (float)a[j] + (float)bb[j] + (float)c[j] + (float)d[j];
#pragma unroll
    for (int j = 0; j < 4; ++j)
        ((float*)&o1)[j] = (float)a[4 + j] + (float)bb[4 + j] + (float)c[4 + j] + (float)d[4 + j];
    out[i * 2]     = o0;
    out[i * 2 + 1] = o1;
}

extern "C" void kernel_launch(void* const* d_in, const int* in_sizes, int n_in,
                              void* d_out, int out_size, void* d_ws, size_t ws_size,
                              hipStream_t stream) {
    const float* x  = (const float*)d_in[0];   // (4,64,64,64)
    const float* bw = (const float*)d_in[1];   // (128,576)
    const float* sw = (const float*)d_in[2];   // (128,576,8)
    const float* sc = (const float*)d_in[3];   // (128,576)
    float* out = (float*)d_out;                // (4,128,64,64) fp32

    __hip_bfloat16* Wp = (__hip_bfloat16*)d_ws;
    __hip_bfloat16* F  = (__hip_bfloat16*)((char*)d_ws + WP_BYTES);
    _Float16*       P  = (_Float16*)((char*)d_ws + P_OFFSET);

    prep_kernel<<<528 + 2592, 256, 0, stream>>>(x, F, bw, sw, sc, Wp);
    gemm_kernel<<<512, 256, 0, stream>>>(F, Wp, P);
    reduce_kernel<<<1024, 256, 0, stream>>>((const half8*)P, (float4*)out);
}